// Round 5
// baseline (12030.801 us; speedup 1.0000x reference)
//
#include <hip/hip_runtime.h>
#include <math.h>

// Round 5: register-resident weights + v_dot2_f32_f16.
// 64 blocks (block = batch), 768 threads (12 waves). Thread owns 3 rows of the
// 2304-row stack [W_base; Wa0..7]: rows tid, tid+768, tid+1536. Weights are
// fp16 pairs: 80 uint4 (320 pairs) pinned in VGPRs for the whole kernel, the
// last 16 uint4 (rows tid+1536, cols 128..255) streamed from L2 each step
// (196 KB/CU/step, issued early, hidden under dots). r state is split fp16:
// r = rh + rl * 2^-11 (rl pre-scaled by 2^11; Sterbenz => split is exact), so
// dot accuracy matches fp32-r with fp16 weights. Dot loop reads rh/rl as
// wave-uniform LDS b128 broadcasts (conflict-free). No inter-block sync.

#define BATCH 64
#define TT    512
#define NN    256
#define ADIM  8
#define NMAT  9
#define ROWS  (NMAT * NN)     // 2304
#define NTHR  768             // 12 waves
#define KQ    32              // 32 uint4 (=128 fp16 pairs) per row
#define REG_KQ2 16            // row-2 uint4 kept in regs; rest streamed

typedef _Float16 half2_t __attribute__((ext_vector_type(2)));

static __device__ __forceinline__ half2_t u2h(unsigned int u) {
  union { unsigned int u; half2_t h; } c; c.u = u; return c.h;
}

// 4 pair-dots of one uint4 of weights against rh/rl uint4 blocks
static __device__ __forceinline__ void dot4(uint4 w, uint4 rh, uint4 rl,
                                            float& ah, float& al) {
  ah = __builtin_amdgcn_fdot2(u2h(w.x), u2h(rh.x), ah, false);
  ah = __builtin_amdgcn_fdot2(u2h(w.y), u2h(rh.y), ah, false);
  ah = __builtin_amdgcn_fdot2(u2h(w.z), u2h(rh.z), ah, false);
  ah = __builtin_amdgcn_fdot2(u2h(w.w), u2h(rh.w), ah, false);
  al = __builtin_amdgcn_fdot2(u2h(w.x), u2h(rl.x), al, false);
  al = __builtin_amdgcn_fdot2(u2h(w.y), u2h(rl.y), al, false);
  al = __builtin_amdgcn_fdot2(u2h(w.z), u2h(rl.z), al, false);
  al = __builtin_amdgcn_fdot2(u2h(w.w), u2h(rl.w), al, false);
}

// ---------------- pre-pass: tiled fp16-pair weights in ws ----------------
// layout: Wt[(g*KQ + kq)*NTHR + tid], g=0..2, kq=0..31; row = g*768 + tid.
__global__ __launch_bounds__(256)
void build_wt_kernel(const float* __restrict__ Wo,
                     const float* __restrict__ Wa,
                     const float* __restrict__ J0,
                     uint4* __restrict__ Wt)
{
  const int q     = blockIdx.x * 256 + threadIdx.x;   // 0..73727
  const int gkq   = q / NTHR;                          // 0..95
  const int tid_t = q - gkq * NTHR;                    // 0..767
  const int g     = gkq >> 5;
  const int kq    = gkq & 31;
  const int row   = g * NTHR + tid_t;                  // 0..2303
  const int mat   = row >> 8;
  const int i     = row & 255;
  const int c0    = kq * 8;
  float v[8];
  if (mat == 0) {
    #pragma unroll
    for (int j = 0; j < 8; ++j)
      v[j] = J0[i * NN + c0 + j] + 0.1f * Wo[i * NN + c0 + j];   // J0 + J1*Wo
  } else {
    const float* src = Wa + ((size_t)(mat - 1) * NN + i) * NN + c0;
    #pragma unroll
    for (int j = 0; j < 8; ++j) v[j] = src[j];
  }
  unsigned int p[4];
  #pragma unroll
  for (int j = 0; j < 4; ++j) {
    _Float16 hl = (_Float16)v[2 * j];      // RNE
    _Float16 hh = (_Float16)v[2 * j + 1];
    unsigned short sl, sh;
    __builtin_memcpy(&sl, &hl, 2);
    __builtin_memcpy(&sh, &hh, 2);
    p[j] = (unsigned int)sl | ((unsigned int)sh << 16);
  }
  Wt[(size_t)gkq * NTHR + tid_t] = make_uint4(p[0], p[1], p[2], p[3]);
}

__global__ __launch_bounds__(NTHR, 1)
void ring_main_kernel(const float* __restrict__ act,     // [64,512,8]
                      const float* __restrict__ r_init,  // [64,256]
                      const float* __restrict__ Wd7,     // [256,256]
                      const uint4* __restrict__ Wt,      // tiled fp16 pairs
                      float* __restrict__ out)           // r_hist | bump
{
  __shared__ uint4 rhq[KQ];        // r high fp16, packed pairs (128 uint)
  __shared__ uint4 rlq[KQ];        // r residual*2^11 fp16
  __shared__ float m_s[ROWS];      // per-row dot results
  __shared__ float cvec[NN], svec[NN];
  __shared__ float at_s[ADIM];
  __shared__ float cs_s[4][2];
  __shared__ float sums_s[3];

  const int tid  = threadIdx.x;
  const int wv   = tid >> 6;
  const int lane = tid & 63;
  const int b    = blockIdx.x;

  float* out_r = out;
  float* out_b = out + (size_t)BATCH * TT * NN;

  // ---- init ----
  for (int idx = tid; idx < NN; idx += NTHR) {
    cvec[idx] = Wd7[idx * NN];          // cos(theta_i)
    svec[idx] = Wd7[idx * NN + 64];     // sin(theta_i)
  }
  if (tid < NN) {
    const float rv = r_init[b * NN + tid];
    _Float16 h = (_Float16)rv;
    _Float16 l = (_Float16)((rv - (float)h) * 2048.0f);
    ((_Float16*)rhq)[tid] = h;
    ((_Float16*)rlq)[tid] = l;
  }
  __syncthreads();
  if (tid == 0) {
    float a = 0.f, c2 = 0.f, c = 0.f;
    for (int j = 0; j < NN; ++j) {
      const float cj = cvec[j], sj = svec[j];
      a += cj * cj; c2 += cj * sj; c += sj * sj;
    }
    sums_s[0] = a; sums_s[1] = c2; sums_s[2] = c;
  }

  // ---- load register-resident weights (rows tid, tid+768; tid+1536 lo-half)
  uint4 w0[KQ], w1[KQ], w2[REG_KQ2];
  {
    const uint4* p0 = Wt + (size_t)0 * KQ * NTHR + tid;
    const uint4* p1 = Wt + (size_t)1 * KQ * NTHR + tid;
    const uint4* p2 = Wt + (size_t)2 * KQ * NTHR + tid;
    #pragma unroll
    for (int k = 0; k < KQ; ++k) w0[k] = p0[k * NTHR];
    #pragma unroll
    for (int k = 0; k < KQ; ++k) w1[k] = p1[k * NTHR];
    #pragma unroll
    for (int k = 0; k < REG_KQ2; ++k) w2[k] = p2[k * NTHR];
  }
  const uint4* wtail = Wt + ((size_t)2 * KQ + REG_KQ2) * NTHR + tid;
  __syncthreads();

  const float LSCALE = 1.0f / 2048.0f;

  for (int t = 0; t < TT; ++t) {
    if (tid < ADIM) at_s[tid] = act[((size_t)b * TT + t) * ADIM + tid];

    // issue the streamed tail early (L2-hot, consumed from kq=16)
    uint4 tail[KQ - REG_KQ2];
    #pragma unroll
    for (int q = 0; q < KQ - REG_KQ2; ++q) tail[q] = wtail[q * NTHR];

    // Phase A: dots. rh/rl reads are wave-uniform broadcasts.
    float ah0 = 0.f, al0 = 0.f, ah1 = 0.f, al1 = 0.f, ah2 = 0.f, al2 = 0.f;
    #pragma unroll
    for (int kq = 0; kq < KQ; ++kq) {
      const uint4 rh = rhq[kq];
      const uint4 rl = rlq[kq];
      dot4(w0[kq], rh, rl, ah0, al0);
      dot4(w1[kq], rh, rl, ah1, al1);
      if (kq < REG_KQ2) dot4(w2[kq], rh, rl, ah2, al2);
      else              dot4(tail[kq - REG_KQ2], rh, rl, ah2, al2);
    }
    m_s[tid]            = ah0 + al0 * LSCALE;
    m_s[tid + NTHR]     = ah1 + al1 * LSCALE;
    m_s[tid + 2 * NTHR] = ah2 + al2 * LSCALE;
    __syncthreads();                       // S1: m_s, at_s ready

    // Phase B: combine + tanh-leak + publish r (fp32 out, fp16 split to LDS)
    if (tid < NN) {
      const int i = tid;
      float rec = m_s[i];
      #pragma unroll
      for (int a = 0; a < ADIM; ++a) rec += at_s[a] * m_s[(1 + a) * NN + i];
      // reconstruct current r from split (exact to ~2^-22)
      const float ro = (float)((_Float16*)rhq)[i]
                     + (float)((_Float16*)rlq)[i] * LSCALE;
      const float rn = ro + 0.1f * (tanhf(rec) - ro);    // DT/TAU = 0.1
      out_r[((size_t)b * TT + t) * NN + i] = rn;
      float cp = cvec[i] * rn, sp = svec[i] * rn;
      #pragma unroll
      for (int m = 1; m < 64; m <<= 1) {
        cp += __shfl_xor(cp, m);
        sp += __shfl_xor(sp, m);
      }
      __syncthreads();                     // S1b: all m_s reads done
      _Float16 h = (_Float16)rn;
      _Float16 l = (_Float16)((rn - (float)h) * 2048.0f);
      ((_Float16*)rhq)[i] = h;
      ((_Float16*)rlq)[i] = l;
      if (lane == 0) { cs_s[wv][0] = cp; cs_s[wv][1] = sp; }
    } else {
      __syncthreads();                     // matching S1b
    }
    __syncthreads();                       // S2: rh/rl, cs_s ready

    // Phase C: bump output (other waves roll into next step's Phase A)
    if (tid < NN) {
      const int i = tid;
      const float C = cs_s[0][0] + cs_s[1][0] + cs_s[2][0] + cs_s[3][0];
      const float S = cs_s[0][1] + cs_s[1][1] + cs_s[2][1] + cs_s[3][1];
      const float n2 = sums_s[0] * C * C + 2.f * sums_s[1] * C * S
                     + sums_s[2] * S * S;
      out_b[((size_t)b * TT + t) * NN + i] =
          (cvec[i] * C + svec[i] * S) * (1.0f / sqrtf(n2));
    }
    // next Phase A reads rhq/rlq (stable since S2) and writes m_s (consumed
    // before S1b); at_s rewritten only after S2. No extra sync needed.
  }
}

extern "C" void kernel_launch(void* const* d_in, const int* in_sizes, int n_in,
                              void* d_out, int out_size, void* d_ws, size_t ws_size,
                              hipStream_t stream) {
  const float* act    = (const float*)d_in[0];
  const float* r_init = (const float*)d_in[1];
  const float* Wo     = (const float*)d_in[2];
  const float* Wa     = (const float*)d_in[3];
  const float* J0     = (const float*)d_in[4];
  const float* Wd7    = (const float*)d_in[5];
  float* out = (float*)d_out;
  uint4* Wt  = (uint4*)d_ws;   // 96*768 uint4 = 1.125 MiB

  hipLaunchKernelGGL(build_wt_kernel, dim3(288), dim3(256), 0, stream,
                     Wo, Wa, J0, Wt);
  hipLaunchKernelGGL(ring_main_kernel, dim3(BATCH), dim3(NTHR), 0, stream,
                     act, r_init, Wd7, (const uint4*)Wt, out);
}